// Round 1
// baseline (371.257 us; speedup 1.0000x reference)
//
#include <hip/hip_runtime.h>
#include <hip/hip_bf16.h>

// Yoshida 4th-order integrator, low-rank christoffel Gamma(v) = W @ (U v)^2.
// B=4096, D=1024, R=256. fp32 baseline (no fp32 MFMA on CDNA4 -> vector ALU).
// Structure per step k: A-kernel H2 = (V U^T)^2  [B,R]; B-kernel Gamma = H2 W^T,
// fused v/x update. x-updates accumulate incrementally (accel ignores x).
// State lives in d_out: [0,BD) = x, [BD,2BD) = v. d_ws holds H2 (B*R fp32 = 4MB).

#define BSZ 4096
#define DD 1024
#define RR 256

#define TM 64
#define TN 64
#define BK 16

// ---------------- A-kernel: H2[b,r] = (sum_d U[r,d]*V[b,d])^2 ----------------
__global__ __launch_bounds__(256) void yoshida_hsq_kernel(
    const float* __restrict__ V,   // [B, D]
    const float* __restrict__ U,   // [R, D]
    float* __restrict__ H2)        // [B, R]
{
    __shared__ __align__(16) float Vs[BK][TM + 4];
    __shared__ __align__(16) float Us[BK][TN + 4];

    const int tid = threadIdx.x;
    const int bm = blockIdx.x * TM;   // batch-row tile
    const int bn = blockIdx.y * TN;   // r tile
    const int tx = tid & 15;
    const int ty = tid >> 4;
    const int lk = tid & (BK - 1);    // 0..15 (k within tile)
    const int lrow = tid / BK;        // 0..15

    float acc[4][4] = {};

    for (int k0 = 0; k0 < DD; k0 += BK) {
        #pragma unroll
        for (int i = 0; i < 4; i++) {
            int row = lrow + 16 * i;
            Vs[lk][row] = V[(size_t)(bm + row) * DD + k0 + lk];
            Us[lk][row] = U[(size_t)(bn + row) * DD + k0 + lk];
        }
        __syncthreads();

        #pragma unroll
        for (int kk = 0; kk < BK; kk++) {
            const float4 av = *reinterpret_cast<const float4*>(&Vs[kk][ty * 4]);
            const float4 bv = *reinterpret_cast<const float4*>(&Us[kk][tx * 4]);
            const float a[4] = {av.x, av.y, av.z, av.w};
            const float b[4] = {bv.x, bv.y, bv.z, bv.w};
            #pragma unroll
            for (int i = 0; i < 4; i++)
                #pragma unroll
                for (int j = 0; j < 4; j++)
                    acc[i][j] += a[i] * b[j];
        }
        __syncthreads();
    }

    #pragma unroll
    for (int i = 0; i < 4; i++) {
        const int b_ = bm + ty * 4 + i;
        float4 o;
        o.x = acc[i][0] * acc[i][0];
        o.y = acc[i][1] * acc[i][1];
        o.z = acc[i][2] * acc[i][2];
        o.w = acc[i][3] * acc[i][3];
        *reinterpret_cast<float4*>(&H2[(size_t)b_ * RR + bn + tx * 4]) = o;
    }
}

// --- B-kernel: Gamma[b,d] = sum_r H2[b,r]*W[d,r]; fused v/x update ----------
// v_new = tv + dcoef_dt*(force - Gamma); x_out = x_prev + xcold_dt*tv + xcnew_dt*v_new
// NOTE: tv/v_out and x_prev/x_out may alias (steps 2,3) -> no __restrict__ there.
__global__ __launch_bounds__(256) void yoshida_gamma_update_kernel(
    const float* __restrict__ H2,     // [B, R]
    const float* __restrict__ Wm,     // [D, R]
    const float* __restrict__ force,  // [B, D]
    const float* tv,                  // [B, D] current velocity
    const float* x_prev,              // [B, D]
    float* v_out,                     // [B, D]
    float* x_out,                     // [B, D]
    float dcoef_dt, float xcold_dt, float xcnew_dt)
{
    __shared__ __align__(16) float Hs[BK][TM + 4];
    __shared__ __align__(16) float Ws[BK][TN + 4];

    const int tid = threadIdx.x;
    const int bm = blockIdx.x * TM;   // batch-row tile
    const int bn = blockIdx.y * TN;   // d tile
    const int tx = tid & 15;
    const int ty = tid >> 4;
    const int lk = tid & (BK - 1);
    const int lrow = tid / BK;

    float acc[4][4] = {};

    for (int k0 = 0; k0 < RR; k0 += BK) {
        #pragma unroll
        for (int i = 0; i < 4; i++) {
            int row = lrow + 16 * i;
            Hs[lk][row] = H2[(size_t)(bm + row) * RR + k0 + lk];
            Ws[lk][row] = Wm[(size_t)(bn + row) * RR + k0 + lk]; // W[d=bn+row][r=k0+lk]
        }
        __syncthreads();

        #pragma unroll
        for (int kk = 0; kk < BK; kk++) {
            const float4 av = *reinterpret_cast<const float4*>(&Hs[kk][ty * 4]);
            const float4 bv = *reinterpret_cast<const float4*>(&Ws[kk][tx * 4]);
            const float a[4] = {av.x, av.y, av.z, av.w};
            const float b[4] = {bv.x, bv.y, bv.z, bv.w};
            #pragma unroll
            for (int i = 0; i < 4; i++)
                #pragma unroll
                for (int j = 0; j < 4; j++)
                    acc[i][j] += a[i] * b[j];
        }
        __syncthreads();
    }

    #pragma unroll
    for (int i = 0; i < 4; i++) {
        const int b_ = bm + ty * 4 + i;
        const size_t base = (size_t)b_ * DD + bn + tx * 4;
        const float4 f4 = *reinterpret_cast<const float4*>(&force[base]);
        const float4 tv4 = *reinterpret_cast<const float4*>(&tv[base]);
        const float4 xp4 = *reinterpret_cast<const float4*>(&x_prev[base]);
        float4 vn, xn;
        vn.x = tv4.x + dcoef_dt * (f4.x - acc[i][0]);
        vn.y = tv4.y + dcoef_dt * (f4.y - acc[i][1]);
        vn.z = tv4.z + dcoef_dt * (f4.z - acc[i][2]);
        vn.w = tv4.w + dcoef_dt * (f4.w - acc[i][3]);
        xn.x = xp4.x + xcold_dt * tv4.x + xcnew_dt * vn.x;
        xn.y = xp4.y + xcold_dt * tv4.y + xcnew_dt * vn.y;
        xn.z = xp4.z + xcold_dt * tv4.z + xcnew_dt * vn.z;
        xn.w = xp4.w + xcold_dt * tv4.w + xcnew_dt * vn.w;
        *reinterpret_cast<float4*>(&v_out[base]) = vn;
        *reinterpret_cast<float4*>(&x_out[base]) = xn;
    }
}

extern "C" void kernel_launch(void* const* d_in, const int* in_sizes, int n_in,
                              void* d_out, int out_size, void* d_ws, size_t ws_size,
                              hipStream_t stream) {
    const float* x     = (const float*)d_in[0];  // [B, D]
    const float* v     = (const float*)d_in[1];  // [B, D]
    const float* force = (const float*)d_in[2];  // [B, D]
    const float* U     = (const float*)d_in[3];  // [R, D]
    const float* W     = (const float*)d_in[4];  // [D, R]

    float* x_out = (float*)d_out;                        // [B, D]
    float* v_out = (float*)d_out + (size_t)BSZ * DD;     // [B, D]
    float* H2    = (float*)d_ws;                         // [B, R]

    // Yoshida coefficients (double precision, cast at use)
    const double dt  = 0.01 * 1.0;
    const double w1  = 1.0 / (2.0 - 1.2599210498948732);     // 1/(2-2^(1/3))
    const double w0  = -1.2599210498948732 * w1;
    const double c1  = w1 / 2.0;
    const double c2  = (w0 + w1) / 2.0;
    const double c3  = c2;
    const double c4  = c1;
    const double dd1 = w1, dd2 = w0, dd3 = w1;

    dim3 blk(256);
    dim3 grdA(BSZ / TM, RR / TN);   // (64, 4)
    dim3 grdB(BSZ / TM, DD / TN);   // (64, 16)

    // Step 1: v1 = v + D1*dt*a(v); x_acc = x + dt*(C1*v + C2*v1)
    yoshida_hsq_kernel<<<grdA, blk, 0, stream>>>(v, U, H2);
    yoshida_gamma_update_kernel<<<grdB, blk, 0, stream>>>(
        H2, W, force, v, x, v_out, x_out,
        (float)(dd1 * dt), (float)(c1 * dt), (float)(c2 * dt));

    // Step 2: v2 = v1 + D2*dt*a(v1); x_acc += C3*dt*v2
    yoshida_hsq_kernel<<<grdA, blk, 0, stream>>>(v_out, U, H2);
    yoshida_gamma_update_kernel<<<grdB, blk, 0, stream>>>(
        H2, W, force, v_out, x_out, v_out, x_out,
        (float)(dd2 * dt), 0.0f, (float)(c3 * dt));

    // Step 3: v3 = v2 + D3*dt*a(v2); x_final = x_acc + C4*dt*v3
    yoshida_hsq_kernel<<<grdA, blk, 0, stream>>>(v_out, U, H2);
    yoshida_gamma_update_kernel<<<grdB, blk, 0, stream>>>(
        H2, W, force, v_out, x_out, v_out, x_out,
        (float)(dd3 * dt), 0.0f, (float)(c4 * dt));
}

// Round 2
// 137.984 us; speedup vs baseline: 2.6906x; 2.6906x over previous
//
#include <hip/hip_runtime.h>
#include <hip/hip_bf16.h>

// Yoshida 4th-order integrator, Gamma(v) = W @ (U v)^2, B=4096, D=1024, R=256.
// KEY STRUCTURE: acceleration ignores x and each batch row is independent ->
// fuse ALL THREE steps into one kernel. Block = 16 rows x 1024 threads (16
// waves). Per step: GEMM A (h = v U^T, K=1024, bf16 MFMA) -> square -> H2 in
// LDS -> GEMM B (Gamma = H2 W^T, K=256, bf16 MFMA) -> fp32 register update of
// v and x-accumulator. v round-trips through LDS as bf16 (MFMA input only;
// fp32 state never leaves registers -> no accumulated rounding).
// U/W pre-packed to fragment-major bf16 so every B-frag load is a contiguous
// 1KB wave read (streams from L2: 256 blocks x 3 x 1MB = 768MB -> ~25us bound).

#define BSZ 4096
#define DD 1024
#define RR 256

typedef unsigned short ushort_t;
typedef __attribute__((ext_vector_type(8))) short short8;
typedef __attribute__((ext_vector_type(4))) float f32x4;

__device__ inline ushort_t f2b(float x) {
    union { float f; unsigned int u; } c;
    c.f = x;
    unsigned int lsb = (c.u >> 16) & 1u;
    return (ushort_t)((c.u + 0x7fffu + lsb) >> 16);  // round-to-nearest-even
}

// ---- pack U [R,D] and W [D,R] (fp32) into fragment-major bf16 --------------
// Tile (nt,kt) = 64 lanes x 8 elems: lane l covers n = nt*16+(l&15),
// k = kt*32+(l>>4)*8+j. GEMM A: n=r,k=d (U row-major, K-contig). GEMM B: n=d,
// k=r (W row-major, K-contig). 65536 groups of 8.
__global__ __launch_bounds__(256) void pack_uw_kernel(
    const float* __restrict__ U, const float* __restrict__ W,
    ushort_t* __restrict__ Upk, ushort_t* __restrict__ Wpk)
{
    const int g = blockIdx.x * 256 + threadIdx.x;
    if (g < 32768) {                       // U: 256*1024/8 groups
        const int l = g & 63;
        const int kt = (g >> 6) & 31, nt = g >> 11;
        const int r = nt * 16 + (l & 15);
        const int d = kt * 32 + (l >> 4) * 8;
        const float* src = U + (size_t)r * DD + d;
        ushort_t* dst = Upk + (size_t)g * 8;
        #pragma unroll
        for (int j = 0; j < 8; ++j) dst[j] = f2b(src[j]);
    } else {                               // W: 1024*256/8 groups
        const int g2 = g - 32768;
        const int l = g2 & 63;
        const int kt = (g2 >> 6) & 7, dtile = g2 >> 9;
        const int d = dtile * 16 + (l & 15);
        const int r = kt * 32 + (l >> 4) * 8;
        const float* src = W + (size_t)d * RR + r;
        ushort_t* dst = Wpk + (size_t)g2 * 8;
        #pragma unroll
        for (int j = 0; j < 8; ++j) dst[j] = f2b(src[j]);
    }
}

// ---- fused 3-step integrator ----------------------------------------------
__global__ __launch_bounds__(1024) void yoshida_fused_kernel(
    const float* __restrict__ x_in,
    const float* __restrict__ v_in,
    const float* __restrict__ force,
    const ushort_t* __restrict__ Upk,
    const ushort_t* __restrict__ Wpk,
    float* __restrict__ x_out,
    float* __restrict__ v_out)
{
    // vS rows padded +8 bf16 (stride 516 words %32 = 4 -> 2-way LDS aliasing, free)
    __shared__ __align__(16) ushort_t vS[16][1032];
    __shared__ __align__(16) ushort_t H2S[16][264];

    const int tid = threadIdx.x;
    const int w = tid >> 6;        // wave 0..15
    const int l = tid & 63;
    const int m = l & 15;          // n / m index within MFMA tile
    const int q = l >> 4;          // quad
    const int b0 = blockIdx.x * 16;
    const int d0 = w * 64;         // this wave's 64-column ownership slice

    // Yoshida coefficients (compile-time doubles, match reference)
    constexpr double CBRT2 = 1.2599210498948731647672106072782;
    constexpr double W1c = 1.0 / (2.0 - CBRT2);
    constexpr double W0c = -CBRT2 * W1c;
    constexpr double DTd = 0.01 * 1.0;
    const float dcoef[3] = {(float)(W1c * DTd), (float)(W0c * DTd), (float)(W1c * DTd)};
    const float xcoef[3] = {(float)((W0c + W1c) * 0.5), (float)((W0c + W1c) * 0.5),
                            (float)(W1c * 0.5)};
    const float c1  = (float)(W1c * 0.5);
    const float dtf = (float)DTd;

    // --- stage v tile into LDS as bf16 (coalesced: thread = 16 consecutive) ---
    {
        const int row = tid >> 6;
        const int col = (tid & 63) * 16;
        const float* src = v_in + (size_t)(b0 + row) * DD + col;
        ushort_t tmp[16];
        #pragma unroll
        for (int j = 0; j < 16; ++j) tmp[j] = f2b(src[j]);
        *(short8*)&vS[row][col]     = *(short8*)&tmp[0];
        *(short8*)&vS[row][col + 8] = *(short8*)&tmp[8];
    }

    // --- per-lane fp32 state in C/D layout: row=q*4+i, col=d0+t*16+m ---------
    float vreg[16], xacc[16];
    #pragma unroll
    for (int t = 0; t < 4; ++t)
        #pragma unroll
        for (int i = 0; i < 4; ++i) {
            const int row = q * 4 + i, col = d0 + t * 16 + m;
            const float vv = v_in[(size_t)(b0 + row) * DD + col];
            vreg[t * 4 + i] = vv;
            xacc[t * 4 + i] = c1 * vv;   // x_final = x + dt*(C1 v0 + C2 v1 + C3 v2 + C4 v3)
        }
    __syncthreads();

    for (int s = 0; s < 3; ++s) {
        // ---- GEMM A: h[b_local, r=w*16+m] over K=1024 (32 k-steps) ----------
        f32x4 accA = {0.f, 0.f, 0.f, 0.f};
        const ushort_t* up = Upk + (size_t)(w * 16384 + l * 8);  // wave's 32KB chunk
        #pragma unroll 4
        for (int kt = 0; kt < 32; ++kt) {
            short8 a = *(const short8*)&vS[m][kt * 32 + q * 8];
            short8 b = *(const short8*)(up + (size_t)kt * 512);
            accA = __builtin_amdgcn_mfma_f32_16x16x32_bf16(a, b, accA, 0, 0, 0);
        }
        #pragma unroll
        for (int i = 0; i < 4; ++i) {
            const float h = accA[i];
            H2S[q * 4 + i][w * 16 + m] = f2b(h * h);
        }
        __syncthreads();   // H2S ready; all vS reads of this step done

        // ---- GEMM B: Gamma[b_local, d=d0+t*16+m] over K=256 (8 k-steps) -----
        f32x4 accB[4];
        #pragma unroll
        for (int t = 0; t < 4; ++t) accB[t] = (f32x4){0.f, 0.f, 0.f, 0.f};
        const ushort_t* wp = Wpk + (size_t)(w * 16384 + l * 8);
        #pragma unroll 2
        for (int kt = 0; kt < 8; ++kt) {
            short8 a = *(const short8*)&H2S[m][kt * 32 + q * 8];
            #pragma unroll
            for (int t = 0; t < 4; ++t) {
                short8 b = *(const short8*)(wp + (size_t)(t * 8 + kt) * 512);
                accB[t] = __builtin_amdgcn_mfma_f32_16x16x32_bf16(a, b, accB[t], 0, 0, 0);
            }
        }

        // ---- epilogue: v += d*dt*(f - Gamma); xacc += c*v; vS <- bf16(v) ----
        const float ddt = dcoef[s], cx = xcoef[s];
        #pragma unroll
        for (int t = 0; t < 4; ++t)
            #pragma unroll
            for (int i = 0; i < 4; ++i) {
                const int row = q * 4 + i, col = d0 + t * 16 + m;
                const float fo = force[(size_t)(b0 + row) * DD + col];
                const float vn = vreg[t * 4 + i] + ddt * (fo - accB[t][i]);
                vreg[t * 4 + i] = vn;
                xacc[t * 4 + i] += cx * vn;
                vS[row][col] = f2b(vn);
            }
        __syncthreads();   // vS ready for next step; H2S reads done
    }

    // ---- final stores: x = x_in + dt*xacc; v = vreg -------------------------
    #pragma unroll
    for (int t = 0; t < 4; ++t)
        #pragma unroll
        for (int i = 0; i < 4; ++i) {
            const int row = q * 4 + i, col = d0 + t * 16 + m;
            const size_t g = (size_t)(b0 + row) * DD + col;
            x_out[g] = x_in[g] + dtf * xacc[t * 4 + i];
            v_out[g] = vreg[t * 4 + i];
        }
}

extern "C" void kernel_launch(void* const* d_in, const int* in_sizes, int n_in,
                              void* d_out, int out_size, void* d_ws, size_t ws_size,
                              hipStream_t stream) {
    const float* x     = (const float*)d_in[0];
    const float* v     = (const float*)d_in[1];
    const float* force = (const float*)d_in[2];
    const float* U     = (const float*)d_in[3];
    const float* W     = (const float*)d_in[4];

    float* x_out = (float*)d_out;
    float* v_out = x_out + (size_t)BSZ * DD;

    ushort_t* Upk = (ushort_t*)d_ws;               // 512 KB
    ushort_t* Wpk = Upk + (size_t)RR * DD;         // 512 KB

    pack_uw_kernel<<<dim3(256), dim3(256), 0, stream>>>(U, W, Upk, Wpk);
    yoshida_fused_kernel<<<dim3(BSZ / 16), dim3(1024), 0, stream>>>(
        x, v, force, Upk, Wpk, x_out, v_out);
}

// Round 3
// 137.932 us; speedup vs baseline: 2.6916x; 1.0004x over previous
//
#include <hip/hip_runtime.h>
#include <hip/hip_bf16.h>

// Yoshida 4th-order integrator, Gamma(v) = W @ (U v)^2, B=4096, D=1024, R=256.
// Fused 3-step kernel: block = 16 batch rows x 1024 threads (16 waves).
// Per step: GEMM A (h = v U^T, K=1024, bf16 MFMA) -> square -> H2 in LDS ->
// GEMM B (Gamma = H2 W^T, K=256) -> fp32 register update of v / x-accumulator.
// Bottleneck (R2 rocprof): per-CU L2 port streaming 3MB of packed U/W
// fragments (~21us floor). This version: 4-deep register prefetch pipelines
// on both GEMMs, cross-barrier prefetch (W before H2S barrier, next-step U
// during epilogue), 2 independent MFMA chains in GEMM A, force cached in
// registers, A-frag hoisted in GEMM B. Pack kernel vectorized (was ~70us!).

#define BSZ 4096
#define DD 1024
#define RR 256

typedef unsigned short ushort_t;
typedef __attribute__((ext_vector_type(8))) short short8;
typedef __attribute__((ext_vector_type(4))) float f32x4;

__device__ inline ushort_t f2b(float x) {
    union { float f; unsigned int u; } c;
    c.f = x;
    unsigned int lsb = (c.u >> 16) & 1u;
    return (ushort_t)((c.u + 0x7fffu + lsb) >> 16);  // round-to-nearest-even
}

// ---- pack U [R,D] and W [D,R] (fp32) into fragment-major bf16 --------------
// Fragment tile (nt,kt): lane l covers n = nt*16+(l&15), k = kt*32+(l>>4)*8+j.
// Each thread: 2x float4 load + 1x short8 (16B) store.
__global__ __launch_bounds__(256) void pack_uw_kernel(
    const float* __restrict__ U, const float* __restrict__ W,
    ushort_t* __restrict__ Upk, ushort_t* __restrict__ Wpk)
{
    const int g = blockIdx.x * 256 + threadIdx.x;
    const float* src;
    ushort_t* dst;
    if (g < 32768) {                       // U: 256*1024/8 groups
        const int l = g & 63;
        const int kt = (g >> 6) & 31, nt = g >> 11;
        src = U + (size_t)(nt * 16 + (l & 15)) * DD + kt * 32 + (l >> 4) * 8;
        dst = Upk + (size_t)g * 8;
    } else {                               // W: 1024*256/8 groups
        const int g2 = g - 32768;
        const int l = g2 & 63;
        const int kt = (g2 >> 6) & 7, dtile = g2 >> 9;
        src = W + (size_t)(dtile * 16 + (l & 15)) * RR + kt * 32 + (l >> 4) * 8;
        dst = Wpk + (size_t)g2 * 8;
    }
    const float4 a = *reinterpret_cast<const float4*>(src);
    const float4 b = *reinterpret_cast<const float4*>(src + 4);
    ushort_t t[8] = {f2b(a.x), f2b(a.y), f2b(a.z), f2b(a.w),
                     f2b(b.x), f2b(b.y), f2b(b.z), f2b(b.w)};
    *reinterpret_cast<short8*>(dst) = *reinterpret_cast<short8*>(t);
}

// ---- fused 3-step integrator ----------------------------------------------
__global__ __launch_bounds__(1024) void yoshida_fused_kernel(
    const float* __restrict__ x_in,
    const float* __restrict__ v_in,
    const float* __restrict__ force,
    const ushort_t* __restrict__ Upk,
    const ushort_t* __restrict__ Wpk,
    float* __restrict__ x_out,
    float* __restrict__ v_out)
{
    // pitch 1032 ushorts = 516 words, %32 == 4 -> minimal aliasing on b128 reads
    __shared__ __align__(16) ushort_t vS[16][1032];
    __shared__ __align__(16) ushort_t H2S[16][264];

    const int tid = threadIdx.x;
    const int w = tid >> 6;        // wave 0..15
    const int l = tid & 63;
    const int m = l & 15;
    const int q = l >> 4;
    const int b0 = blockIdx.x * 16;
    const int d0 = w * 64;         // wave's 64-column slice (GEMM B / epilogue)

    constexpr double CBRT2 = 1.2599210498948731647672106072782;
    constexpr double W1c = 1.0 / (2.0 - CBRT2);
    constexpr double W0c = -CBRT2 * W1c;
    constexpr double DTd = 0.01 * 1.0;
    const float dcoef[3] = {(float)(W1c * DTd), (float)(W0c * DTd), (float)(W1c * DTd)};
    const float xcoef[3] = {(float)((W0c + W1c) * 0.5), (float)((W0c + W1c) * 0.5),
                            (float)(W1c * 0.5)};
    const float c1  = (float)(W1c * 0.5);
    const float dtf = (float)DTd;

    // --- per-lane fp32 state + force cached in registers (C/D layout) -------
    float vreg[16], xacc[16], freg[16];
    #pragma unroll
    for (int t = 0; t < 4; ++t)
        #pragma unroll
        for (int i = 0; i < 4; ++i) {
            const size_t gidx = (size_t)(b0 + q * 4 + i) * DD + d0 + t * 16 + m;
            const float vv = v_in[gidx];
            vreg[t * 4 + i] = vv;
            xacc[t * 4 + i] = c1 * vv;
            freg[t * 4 + i] = force[gidx];
        }

    // --- stage v tile into LDS as bf16 (thread = 16 consecutive floats) -----
    {
        const int row = tid >> 6;
        const int col = (tid & 63) * 16;
        const float* sp = v_in + (size_t)(b0 + row) * DD + col;
        const float4 f0 = *reinterpret_cast<const float4*>(sp);
        const float4 f1 = *reinterpret_cast<const float4*>(sp + 4);
        const float4 f2 = *reinterpret_cast<const float4*>(sp + 8);
        const float4 f3 = *reinterpret_cast<const float4*>(sp + 12);
        ushort_t tmp[16] = {f2b(f0.x), f2b(f0.y), f2b(f0.z), f2b(f0.w),
                            f2b(f1.x), f2b(f1.y), f2b(f1.z), f2b(f1.w),
                            f2b(f2.x), f2b(f2.y), f2b(f2.z), f2b(f2.w),
                            f2b(f3.x), f2b(f3.y), f2b(f3.z), f2b(f3.w)};
        *reinterpret_cast<short8*>(&vS[row][col])     = *reinterpret_cast<short8*>(&tmp[0]);
        *reinterpret_cast<short8*>(&vS[row][col + 8]) = *reinterpret_cast<short8*>(&tmp[8]);
    }

    const ushort_t* up = Upk + (size_t)(w * 16384 + l * 8);  // wave's 32KB U chunk
    const ushort_t* wp = Wpk + (size_t)(w * 16384 + l * 8);  // wave's 32KB W chunk

    // --- preload U prefetch pipeline (depth 4) ------------------------------
    short8 ub[4];
    #pragma unroll
    for (int p = 0; p < 4; ++p)
        ub[p] = *reinterpret_cast<const short8*>(up + (size_t)p * 512);

    #pragma unroll
    for (int s = 0; s < 3; ++s) {
        __syncthreads();   // s==0: vS staged; s>0: epilogue vS writes + H2S reads done

        // ---- GEMM A: h[b_local, r=w*16+m], K=1024, 2 independent chains ----
        f32x4 a0 = {0.f, 0.f, 0.f, 0.f}, a1 = {0.f, 0.f, 0.f, 0.f};
        #pragma unroll
        for (int kt = 0; kt < 32; ++kt) {
            const short8 b = ub[kt & 3];
            if (kt < 28)
                ub[kt & 3] = *reinterpret_cast<const short8*>(up + (size_t)(kt + 4) * 512);
            const short8 a = *reinterpret_cast<const short8*>(&vS[m][kt * 32 + q * 8]);
            if (kt & 1) a1 = __builtin_amdgcn_mfma_f32_16x16x32_bf16(a, b, a1, 0, 0, 0);
            else        a0 = __builtin_amdgcn_mfma_f32_16x16x32_bf16(a, b, a0, 0, 0, 0);
        }
        #pragma unroll
        for (int i = 0; i < 4; ++i) {
            const float h = a0[i] + a1[i];
            H2S[q * 4 + i][w * 16 + m] = f2b(h * h);
        }

        // ---- prefetch W kt=0 chunks BEFORE the barrier (no H2S dependency) -
        short8 wb[4];
        #pragma unroll
        for (int t = 0; t < 4; ++t)
            wb[t] = *reinterpret_cast<const short8*>(wp + (size_t)(t * 8) * 512);
        __syncthreads();   // H2S published

        // ---- GEMM B: Gamma[b_local, d=d0+t*16+m], K=256 ---------------------
        f32x4 accB[4];
        #pragma unroll
        for (int t = 0; t < 4; ++t) accB[t] = (f32x4){0.f, 0.f, 0.f, 0.f};
        #pragma unroll
        for (int kt = 0; kt < 8; ++kt) {
            const short8 a = *reinterpret_cast<const short8*>(&H2S[m][kt * 32 + q * 8]);
            #pragma unroll
            for (int t = 0; t < 4; ++t) {
                const short8 b = wb[t];
                if (kt < 7)
                    wb[t] = *reinterpret_cast<const short8*>(wp + (size_t)(t * 8 + kt + 1) * 512);
                accB[t] = __builtin_amdgcn_mfma_f32_16x16x32_bf16(a, b, accB[t], 0, 0, 0);
            }
        }

        // ---- epilogue: v += d*dt*(f - Gamma); xacc += c*v; vS <- bf16(v) ----
        const float ddt = dcoef[s], cx = xcoef[s];
        #pragma unroll
        for (int t = 0; t < 4; ++t)
            #pragma unroll
            for (int i = 0; i < 4; ++i) {
                const float vn = vreg[t * 4 + i] + ddt * (freg[t * 4 + i] - accB[t][i]);
                vreg[t * 4 + i] = vn;
                xacc[t * 4 + i] += cx * vn;
                vS[q * 4 + i][d0 + t * 16 + m] = f2b(vn);
            }

        // ---- refill U pipeline for next step (overlaps barrier drain) -------
        if (s < 2) {
            #pragma unroll
            for (int p = 0; p < 4; ++p)
                ub[p] = *reinterpret_cast<const short8*>(up + (size_t)p * 512);
        }
    }

    // ---- final stores: x = x_in + dt*xacc; v = vreg -------------------------
    #pragma unroll
    for (int t = 0; t < 4; ++t)
        #pragma unroll
        for (int i = 0; i < 4; ++i) {
            const size_t g = (size_t)(b0 + q * 4 + i) * DD + d0 + t * 16 + m;
            x_out[g] = x_in[g] + dtf * xacc[t * 4 + i];
            v_out[g] = vreg[t * 4 + i];
        }
}

extern "C" void kernel_launch(void* const* d_in, const int* in_sizes, int n_in,
                              void* d_out, int out_size, void* d_ws, size_t ws_size,
                              hipStream_t stream) {
    const float* x     = (const float*)d_in[0];
    const float* v     = (const float*)d_in[1];
    const float* force = (const float*)d_in[2];
    const float* U     = (const float*)d_in[3];
    const float* W     = (const float*)d_in[4];

    float* x_out = (float*)d_out;
    float* v_out = x_out + (size_t)BSZ * DD;

    ushort_t* Upk = (ushort_t*)d_ws;               // 512 KB
    ushort_t* Wpk = Upk + (size_t)RR * DD;         // 512 KB

    pack_uw_kernel<<<dim3(256), dim3(256), 0, stream>>>(U, W, Upk, Wpk);
    yoshida_fused_kernel<<<dim3(BSZ / 16), dim3(1024), 0, stream>>>(
        x, v, force, Upk, Wpk, x_out, v_out);
}

// Round 4
// 132.817 us; speedup vs baseline: 2.7952x; 1.0385x over previous
//
#include <hip/hip_runtime.h>

// Yoshida 4th-order integrator, Gamma(v) = W @ (U v)^2, B=4096, D=1024, R=256.
// Fused 3-step kernel (validated structure from R2/R3): block = 16 batch rows
// x 1024 threads (16 waves). Per step: GEMM A (h = v U^T, K=1024) -> square ->
// H2 in LDS -> GEMM B (Gamma = H2 W^T, K=256) -> fp32 register v/x update.
// R3 finding: kernel is BANDWIDTH-bound on the per-CU U/W stream (prefetch
// engineering was a no-op; ~21 B/cyc/CU L2 rate). This round: fp8 e4m3
// everywhere (mfma_f32_16x16x32_fp8_fp8, same fragment geometry as bf16) ->
// halves the stream (3.0 -> 1.5 MB/CU) and LDS bytes. U pre-scaled x8, W x16
// at pack time to dodge e4m3 subnormals (U~0.03, W~0.06); compensated exactly:
// h^2 = accA^2/64, Gamma = accB/16 folded into epilogue constants.

#define BSZ 4096
#define DD 1024
#define RR 256

typedef unsigned char uchar;
typedef long long i64;
typedef __attribute__((ext_vector_type(2))) long i64x2;
typedef __attribute__((ext_vector_type(4))) float f32x4;
typedef __attribute__((ext_vector_type(4))) unsigned int uint4v;

// pack 4 floats -> 4 fp8 e4m3 bytes (HW cvt, RNE, saturating)
__device__ inline unsigned int f2q4(float a, float b, float c, float d) {
    int lo = __builtin_amdgcn_cvt_pk_fp8_f32(a, b, 0, false);
    int hi = __builtin_amdgcn_cvt_pk_fp8_f32(c, d, lo, true);
    return (unsigned int)hi;
}
__device__ inline uchar f2q1(float x) {
    return (uchar)(__builtin_amdgcn_cvt_pk_fp8_f32(x, x, 0, false) & 0xff);
}

// ---- pack U [R,D] (x8) and W [D,R] (x16) into fragment-major fp8 -----------
// Fragment pair layout: lane l holds 16 bytes = kt=2p (k=kb..kb+7) then
// kt=2p+1 (k=kb+32..kb+39), kb = p*64 + (l>>4)*8; n = tile*16 + (l&15).
__global__ __launch_bounds__(256) void pack_uw_kernel(
    const float* __restrict__ U, const float* __restrict__ W,
    uchar* __restrict__ Upk, uchar* __restrict__ Wpk)
{
    const int g = blockIdx.x * 256 + threadIdx.x;
    const float* src;
    uchar* dst;
    float sc;
    if (g < 16384) {                       // U: 16 nt x 16 p x 64 l
        const int l = g & 63, p = (g >> 6) & 15, nt = g >> 10;
        src = U + (size_t)(nt * 16 + (l & 15)) * DD + p * 64 + (l >> 4) * 8;
        dst = Upk + ((size_t)nt << 14) + (p << 10) + (l << 4);
        sc = 8.0f;
    } else {                               // W: 64 dtile x 4 p x 64 l
        const int g2 = g - 16384;
        const int l = g2 & 63, p = (g2 >> 6) & 3, dt_ = g2 >> 8;
        src = W + (size_t)(dt_ * 16 + (l & 15)) * RR + p * 64 + (l >> 4) * 8;
        dst = Wpk + ((size_t)dt_ << 12) + (p << 10) + (l << 4);
        sc = 16.0f;
    }
    const float4 x0 = *reinterpret_cast<const float4*>(src);
    const float4 x1 = *reinterpret_cast<const float4*>(src + 4);
    const float4 y0 = *reinterpret_cast<const float4*>(src + 32);
    const float4 y1 = *reinterpret_cast<const float4*>(src + 36);
    uint4v o;
    o.x = f2q4(sc * x0.x, sc * x0.y, sc * x0.z, sc * x0.w);
    o.y = f2q4(sc * x1.x, sc * x1.y, sc * x1.z, sc * x1.w);
    o.z = f2q4(sc * y0.x, sc * y0.y, sc * y0.z, sc * y0.w);
    o.w = f2q4(sc * y1.x, sc * y1.y, sc * y1.z, sc * y1.w);
    *reinterpret_cast<uint4v*>(dst) = o;
}

// ---- fused 3-step integrator ----------------------------------------------
__global__ __launch_bounds__(1024) void yoshida_fused_kernel(
    const float* __restrict__ x_in,
    const float* __restrict__ v_in,
    const float* __restrict__ force,
    const uchar* __restrict__ Upk,
    const uchar* __restrict__ Wpk,
    float* __restrict__ x_out,
    float* __restrict__ v_out)
{
    // byte pitches: 1040 = 260 words (%32==4), 272 = 68 words (%32==4):
    // b64 reads land 2 lanes per bank-pair per phase -> conflict-free (m136)
    __shared__ __align__(16) uchar vS[16][1040];
    __shared__ __align__(16) uchar H2S[16][272];

    const int tid = threadIdx.x;
    const int w = tid >> 6, l = tid & 63;
    const int m = l & 15, q = l >> 4;
    const int b0 = blockIdx.x * 16;
    const int d0 = w * 64;

    constexpr double CBRT2 = 1.2599210498948731647672106072782;
    constexpr double W1c = 1.0 / (2.0 - CBRT2);
    constexpr double W0c = -CBRT2 * W1c;
    constexpr double DTd = 0.01 * 1.0;
    const float dcoef[3] = {(float)(W1c * DTd), (float)(W0c * DTd), (float)(W1c * DTd)};
    const float xcoef[3] = {(float)((W0c + W1c) * 0.5), (float)((W0c + W1c) * 0.5),
                            (float)(W1c * 0.5)};
    const float c1  = (float)(W1c * 0.5);
    const float dtf = (float)DTd;

    // --- per-lane fp32 state + force in registers (MFMA C/D layout) ---------
    float vreg[16], xacc[16], freg[16];
    #pragma unroll
    for (int t = 0; t < 4; ++t)
        #pragma unroll
        for (int i = 0; i < 4; ++i) {
            const size_t gidx = (size_t)(b0 + q * 4 + i) * DD + d0 + t * 16 + m;
            const float vv = v_in[gidx];
            vreg[t * 4 + i] = vv;
            xacc[t * 4 + i] = c1 * vv;
            freg[t * 4 + i] = force[gidx];
        }

    // --- stage v tile into LDS as fp8 (thread = 16 consecutive floats) ------
    {
        const int row = tid >> 6;
        const int col = (tid & 63) * 16;
        const float* sp = v_in + (size_t)(b0 + row) * DD + col;
        const float4 f0 = *reinterpret_cast<const float4*>(sp);
        const float4 f1 = *reinterpret_cast<const float4*>(sp + 4);
        const float4 f2 = *reinterpret_cast<const float4*>(sp + 8);
        const float4 f3 = *reinterpret_cast<const float4*>(sp + 12);
        uint4v pk;
        pk.x = f2q4(f0.x, f0.y, f0.z, f0.w);
        pk.y = f2q4(f1.x, f1.y, f1.z, f1.w);
        pk.z = f2q4(f2.x, f2.y, f2.z, f2.w);
        pk.w = f2q4(f3.x, f3.y, f3.z, f3.w);
        *reinterpret_cast<uint4v*>(&vS[row][col]) = pk;
    }

    const uchar* up = Upk + ((size_t)w << 14) + (l << 4);       // wave's 16KB U
    const uchar* wp = Wpk + ((size_t)(w * 4) << 12) + (l << 4); // wave's 16KB W

    #pragma unroll
    for (int s = 0; s < 3; ++s) {
        __syncthreads();   // s==0: vS staged; s>0: epilogue vS writes visible

        // ---- GEMM A: accA = (8U) . v_q, K=1024, 2 independent chains --------
        f32x4 a0 = {0.f, 0.f, 0.f, 0.f}, a1 = {0.f, 0.f, 0.f, 0.f};
        #pragma unroll
        for (int p = 0; p < 16; ++p) {
            const i64x2 bb = *reinterpret_cast<const i64x2*>(up + (p << 10));
            const i64 af0 = *reinterpret_cast<const i64*>(&vS[m][p * 64 + q * 8]);
            const i64 af1 = *reinterpret_cast<const i64*>(&vS[m][p * 64 + 32 + q * 8]);
            a0 = __builtin_amdgcn_mfma_f32_16x16x32_fp8_fp8(af0, bb.x, a0, 0, 0, 0);
            a1 = __builtin_amdgcn_mfma_f32_16x16x32_fp8_fp8(af1, bb.y, a1, 0, 0, 0);
        }
        #pragma unroll
        for (int i = 0; i < 4; ++i) {
            const float h8 = a0[i] + a1[i];                    // = 8*h
            H2S[q * 4 + i][w * 16 + m] = f2q1(h8 * h8 * 0.015625f);  // h^2
        }
        __syncthreads();   // H2S published

        // ---- GEMM B: accB = (16W) . h2_q, K=256 -----------------------------
        f32x4 accB[4];
        #pragma unroll
        for (int t = 0; t < 4; ++t) accB[t] = (f32x4){0.f, 0.f, 0.f, 0.f};
        #pragma unroll
        for (int p = 0; p < 4; ++p) {
            const i64 ha0 = *reinterpret_cast<const i64*>(&H2S[m][p * 64 + q * 8]);
            const i64 ha1 = *reinterpret_cast<const i64*>(&H2S[m][p * 64 + 32 + q * 8]);
            #pragma unroll
            for (int t = 0; t < 4; ++t) {
                const i64x2 wb = *reinterpret_cast<const i64x2*>(wp + (t << 12) + (p << 10));
                accB[t] = __builtin_amdgcn_mfma_f32_16x16x32_fp8_fp8(ha0, wb.x, accB[t], 0, 0, 0);
                accB[t] = __builtin_amdgcn_mfma_f32_16x16x32_fp8_fp8(ha1, wb.y, accB[t], 0, 0, 0);
            }
        }

        // ---- epilogue: v += ddt*f - (ddt/16)*accB; xacc += cx*v; vS <- fp8(v)
        const float ddt = dcoef[s], cx = xcoef[s], gsc = dcoef[s] * 0.0625f;
        #pragma unroll
        for (int t = 0; t < 4; ++t)
            #pragma unroll
            for (int i = 0; i < 4; ++i) {
                const float vn = vreg[t * 4 + i] + ddt * freg[t * 4 + i]
                                 - gsc * accB[t][i];
                vreg[t * 4 + i] = vn;
                xacc[t * 4 + i] += cx * vn;
                vS[q * 4 + i][d0 + t * 16 + m] = f2q1(vn);
            }
    }

    // ---- final stores: x = x_in + dt*xacc; v = vreg -------------------------
    #pragma unroll
    for (int t = 0; t < 4; ++t)
        #pragma unroll
        for (int i = 0; i < 4; ++i) {
            const size_t g = (size_t)(b0 + q * 4 + i) * DD + d0 + t * 16 + m;
            x_out[g] = x_in[g] + dtf * xacc[t * 4 + i];
            v_out[g] = vreg[t * 4 + i];
        }
}

extern "C" void kernel_launch(void* const* d_in, const int* in_sizes, int n_in,
                              void* d_out, int out_size, void* d_ws, size_t ws_size,
                              hipStream_t stream) {
    const float* x     = (const float*)d_in[0];
    const float* v     = (const float*)d_in[1];
    const float* force = (const float*)d_in[2];
    const float* U     = (const float*)d_in[3];
    const float* W     = (const float*)d_in[4];

    float* x_out = (float*)d_out;
    float* v_out = x_out + (size_t)BSZ * DD;

    uchar* Upk = (uchar*)d_ws;                 // 256 KB
    uchar* Wpk = Upk + (size_t)RR * DD;        // 256 KB

    pack_uw_kernel<<<dim3(128), dim3(256), 0, stream>>>(U, W, Upk, Wpk);
    yoshida_fused_kernel<<<dim3(BSZ / 16), dim3(1024), 0, stream>>>(
        x, v, force, Upk, Wpk, x_out, v_out);
}